// Round 6
// baseline (126.126 us; speedup 1.0000x reference)
//
#include <hip/hip_runtime.h>

#define DK 256   // feature dim (K)
#define TT 1024  // T1 = T2
#define NB 16    // batch

typedef __attribute__((ext_vector_type(8))) short bf16x8;
typedef __attribute__((ext_vector_type(4))) float f32x4;

// HW packed fp32->bf16 (RNE). r[15:0]=bf16(lo), r[31:16]=bf16(hi).
__device__ __forceinline__ unsigned int cvt_pk_bf16(float lo, float hi) {
    unsigned int r;
    asm("v_cvt_pk_bf16_f32 %0, %1, %2" : "=v"(r) : "v"(lo), "v"(hi));
    return r;
}

union BF8 { uint4 u; bf16x8 v; };

// ---------------------------------------------------------------------------
// Fully fused: out[b,i,j] = sum_k bf16(x)[b,i,k]*bf16(w3*y)[b,j,k]
//                           + (x.w1)[b,i] + (y.w2)[b,j]
//
// R11: x staged through LDS via global_load_lds DMA (R9/R10 post-mortem:
// register-level prefetch ALWAYS spills -- acc[2][8]=64 AGPR leaves no
// room for an in-flight x window; both attempts lost to plain R6 (~37us).
// The DMA path holds in-flight data in the VMEM queue + LDS, zero VGPRs):
//  * Xp[2][256x32] fp32 panels (32KB each, dbuf). Iter ks: issue DMA for
//    panel ks+1, compute ks from the other buffer, __syncthreads (vmcnt
//    drain = ready gate; DMA ~580cy ~= compute phase, drain is cheap).
//  * Panels XOR-swizzled via pre-swizzled GLOBAL source (rule 21):
//    LDS[r][slot] holds global chunk (slot ^ (r&7)); reads use same XOR
//    -> 2-way bank conflicts only (free, m136).
//  * LDS 128.5KB -> 1 block/CU, 8 waves. Deliberate: pipelining over TLP
//    (R8 showed more TLP alone doesn't help; chain must break).
//  * y-stage, Bs swizzle, tys, epilogue, grid unchanged from R6.
// ---------------------------------------------------------------------------
__global__ __launch_bounds__(512, 2) void fused_kernel(
    const float* __restrict__ x, const float* __restrict__ y,
    const float* __restrict__ WS, float* __restrict__ out)
{
    __shared__ unsigned short Bs[128 * DK];   // 64 KB  (y bf16, XOR-swizzled)
    __shared__ float Xp[2][256 * 32];         // 2 x 32 KB (x fp32 panels)
    __shared__ float tys[128];

    const int tid  = threadIdx.x;
    const int lane = tid & 63;
    const int w    = tid >> 6;                // wave 0..7

    // XCD-locality decode: id%8 constant across the jt group and the is group
    const int id = blockIdx.x;                // 0..511
    const int b  = id & 15;                   // batch
    const int is = (id >> 4) & 3;             // i slice (0..3), 256 rows
    const int jt = id >> 6;                   // j tile (0..7), 128 cols

    const int i0blk = is * 256;
    const float* gX = x + ((size_t)b * TT + i0blk) * DK;

    // DMA geometry: chunk q = w*4 + t covers panel rows q*8..q*8+8 (1KB LDS,
    // one global_load_lds x 64 lanes x 16B). LDS dest is wave-uniform base;
    // HW adds lane*16. Global src is per-lane, chunk-swizzled.
    const int r_ln = lane >> 3;               // row within 8-row chunk
    const int c_ln = lane & 7;                // 16B slot within row

    // ---- 0. issue DMA for panel 0 (latency hides under the whole y-stage)
    {
        #pragma unroll
        for (int t = 0; t < 4; ++t) {
            const int q = w * 4 + t;
            const int r = q * 8 + r_ln;                   // block-local row
            const int gc = c_ln ^ (r & 7);                // swizzled src chunk
            const float* gp = gX + (size_t)r * DK + gc * 4;
            float* lp = &Xp[0][q * 256];                  // wave-uniform
            __builtin_amdgcn_global_load_lds(
                (const __attribute__((address_space(1))) void*)gp,
                (__attribute__((address_space(3))) void*)lp, 16, 0, 0);
        }
    }

    // ---- 1. stage B = bf16(w3*y) (XOR-swizzled), ty = y.w2
    {
        const float* gY0 = y + ((size_t)b * TT + jt * 128) * DK;
        const int c = tid & 31;               // 16B chunk within row
        const float* w3p = WS + 2 * DK + c * 8;
        const float* w2p = WS + DK + c * 8;
        const float4 wa = *(const float4*)(w3p);
        const float4 wb = *(const float4*)(w3p + 4);
        const float4 va = *(const float4*)(w2p);
        const float4 vb = *(const float4*)(w2p + 4);
        #pragma unroll
        for (int it = 0; it < 8; ++it) {
            const int j = it * 16 + (tid >> 5);   // local row 0..127
            const float* gY = gY0 + (size_t)j * DK + c * 8;
            const float4 ya = *(const float4*)(gY);
            const float4 yb = *(const float4*)(gY + 4);
            float p = ya.x * va.x + ya.y * va.y + ya.z * va.z + ya.w * va.w
                    + yb.x * vb.x + yb.y * vb.y + yb.z * vb.z + yb.w * vb.w;
            uint4 o;
            o.x = cvt_pk_bf16(ya.x * wa.x, ya.y * wa.y);
            o.y = cvt_pk_bf16(ya.z * wa.z, ya.w * wa.w);
            o.z = cvt_pk_bf16(yb.x * wb.x, yb.y * wb.y);
            o.w = cvt_pk_bf16(yb.z * wb.z, yb.w * wb.w);
            const int slot = c ^ (j & 7);
            *(uint4*)(Bs + j * DK + slot * 8) = o;
            // reduce p across the 32 lanes sharing row j
            p += __shfl_xor(p, 1);
            p += __shfl_xor(p, 2);
            p += __shfl_xor(p, 4);
            p += __shfl_xor(p, 8);
            p += __shfl_xor(p, 16);
            if ((tid & 31) == 0) tys[j] = p;
        }
    }
    __syncthreads();    // drains panel-0 DMA (vmcnt 0) + publishes Bs/tys

    // ---- 2. K-loop: compute panel ks from LDS, DMA panel ks+1 meanwhile
    const int mfr  = lane & 15;
    const int quad = lane >> 4;
    const int Rl0  = w * 32 + mfr;            // block-local row, it=0
    const int Rl1  = Rl0 + 16;                // it=1

    f32x4 acc[2][8];
    #pragma unroll
    for (int it = 0; it < 2; ++it)
        #pragma unroll
        for (int n = 0; n < 8; ++n)
            acc[it][n] = (f32x4){0.f, 0.f, 0.f, 0.f};
    float txp[2] = {0.f, 0.f};

    #pragma unroll
    for (int ks = 0; ks < 8; ++ks) {
        // issue next panel's DMA first: its buffer was freed by the barrier
        // at the end of the previous iteration; latency overlaps compute ks
        if (ks < 7) {
            #pragma unroll
            for (int t = 0; t < 4; ++t) {
                const int q = w * 4 + t;
                const int r = q * 8 + r_ln;
                const int gc = c_ln ^ (r & 7);
                const float* gp = gX + (size_t)r * DK + (ks + 1) * 32 + gc * 4;
                float* lp = &Xp[(ks + 1) & 1][q * 256];
                __builtin_amdgcn_global_load_lds(
                    (const __attribute__((address_space(1))) void*)gp,
                    (__attribute__((address_space(3))) void*)lp, 16, 0, 0);
            }
        }

        const float* w1p = WS + ks * 32 + quad * 8;
        const float4 w1a = *(const float4*)(w1p);
        const float4 w1b = *(const float4*)(w1p + 4);
        bf16x8 av[2];
        const int Rl[2] = {Rl0, Rl1};
        #pragma unroll
        for (int it = 0; it < 2; ++it) {
            const float* pr = &Xp[ks & 1][Rl[it] * 32];
            const int s0 = (quad * 2) ^ (Rl[it] & 7);
            const int s1 = (quad * 2 + 1) ^ (Rl[it] & 7);
            const float4 xa = *(const float4*)(pr + s0 * 4);
            const float4 xb = *(const float4*)(pr + s1 * 4);
            txp[it] += xa.x * w1a.x + xa.y * w1a.y + xa.z * w1a.z + xa.w * w1a.w
                     + xb.x * w1b.x + xb.y * w1b.y + xb.z * w1b.z + xb.w * w1b.w;
            BF8 cv;
            cv.u.x = cvt_pk_bf16(xa.x, xa.y);
            cv.u.y = cvt_pk_bf16(xa.z, xa.w);
            cv.u.z = cvt_pk_bf16(xb.x, xb.y);
            cv.u.w = cvt_pk_bf16(xb.z, xb.w);
            av[it] = cv.v;
        }
        #pragma unroll
        for (int n = 0; n < 8; ++n) {
            const int j    = n * 16 + mfr;
            const int slot = (ks * 4 + quad) ^ (j & 7);
            const bf16x8 bv = *(const bf16x8*)(Bs + j * DK + slot * 8);
            #pragma unroll
            for (int it = 0; it < 2; ++it)
                acc[it][n] = __builtin_amdgcn_mfma_f32_16x16x32_bf16(
                    av[it], bv, acc[it][n], 0, 0, 0);
        }

        // ready-gate + buffer-free gate for the next iteration
        if (ks < 7) __syncthreads();
    }

    // ---- 3. epilogue: tx quad-reduction, + tx[i] + ty[j], fp32 stores
    #pragma unroll
    for (int it = 0; it < 2; ++it) {
        txp[it] += __shfl_xor(txp[it], 16);
        txp[it] += __shfl_xor(txp[it], 32);
        // lane now holds full tx for row i0 + it*16 + mfr
    }

    float tyv[8];
    #pragma unroll
    for (int n = 0; n < 8; ++n)
        tyv[n] = tys[n * 16 + mfr];

    const int i0 = i0blk + w * 32;
    float* outB = out + ((size_t)b << 20) + (size_t)i0 * TT + jt * 128;
    #pragma unroll
    for (int it = 0; it < 2; ++it) {
        #pragma unroll
        for (int r = 0; r < 4; ++r) {
            const int row = it * 16 + quad * 4 + r;
            // tx for this row lives at lanes with mfr == quad*4+r (any quad)
            const float trow = __shfl(txp[it], (lane & 48) | (quad * 4 + r));
            #pragma unroll
            for (int n = 0; n < 8; ++n)
                outB[(size_t)row * TT + n * 16 + mfr] =
                    acc[it][n][r] + trow + tyv[n];
        }
    }
}

extern "C" void kernel_launch(void* const* d_in, const int* in_sizes, int n_in,
                              void* d_out, int out_size, void* d_ws, size_t ws_size,
                              hipStream_t stream)
{
    const float* x  = (const float*)d_in[0];
    const float* y  = (const float*)d_in[1];
    const float* WS = (const float*)d_in[2];
    float* out = (float*)d_out;
    (void)d_ws; (void)ws_size;   // no workspace needed — fully fused

    fused_kernel<<<dim3(512), dim3(512), 0, stream>>>(x, y, WS, out);
}

// Round 7
// 118.118 us; speedup vs baseline: 1.0678x; 1.0678x over previous
//
#include <hip/hip_runtime.h>

#define DK 256   // feature dim (K)
#define TT 1024  // T1 = T2
#define NB 16    // batch

typedef __attribute__((ext_vector_type(8))) short bf16x8;
typedef __attribute__((ext_vector_type(4))) float f32x4;

// HW packed fp32->bf16 (RNE). r[15:0]=bf16(lo), r[31:16]=bf16(hi).
__device__ __forceinline__ unsigned int cvt_pk_bf16(float lo, float hi) {
    unsigned int r;
    asm("v_cvt_pk_bf16_f32 %0, %1, %2" : "=v"(r) : "v"(lo), "v"(hi));
    return r;
}

union BF8 { uint4 u; bf16x8 v; };

// ---------------------------------------------------------------------------
// Fully fused: out[b,i,j] = sum_k bf16(x)[b,i,k]*bf16(w3*y)[b,j,k]
//                           + (x.w1)[b,i] + (y.w2)[b,j]
//
// R12 = R11's DMA staging made BARRIER-FREE with counted vmcnt (T4).
// R11 post-mortem: per-iter __syncthreads drains vmcnt(0) (compiler emits
// it before s_barrier) -> prefetch depth ~0 + 8 barrier syncs. But X panels
// are WAVE-PRIVATE (wave w DMAs and reads only rows w*32..w*32+31) -> no
// cross-wave ordering needed at all. Session diagnosis: FETCH 16.5MB =
// re-reads are L2/L3-served; 4MB/XCD working set + output stream overflow
// XCD-L2 -> re-reads at L3 latency (~600-900cy); 80% idle cycles.
//  * K-loop: wait vmcnt(4) [panel ks done, ks+1 in flight] + sched_barrier,
//    ds_read Xp frags, cvt, issue DMA panel ks+2 into freed buffer
//    (distance ~ MFMA section + 1 iter ~ 500-600cy), MFMA cluster. Zero
//    barriers in the loop; 8 waves skew freely.
//  * w1 staged to LDS (lgkm domain) so DMA is the ONLY vmcnt traffic.
//  * One __syncthreads total (publishes Bs/tys/w1s + drains panels 0,1).
//  * Numerics identical to R6/R11 (fp32 x via LDS, same cvt_pk).
// Decision rule: if dur >= 109.6 -> revert to R6 next round, conclude.
// ---------------------------------------------------------------------------
__global__ __launch_bounds__(512, 2) void fused_kernel(
    const float* __restrict__ x, const float* __restrict__ y,
    const float* __restrict__ WS, float* __restrict__ out)
{
    __shared__ unsigned short Bs[128 * DK];   // 64 KB  (y bf16, XOR-swizzled)
    __shared__ float Xp[2][256 * 32];         // 2 x 32 KB (x fp32 panels)
    __shared__ float tys[128];
    __shared__ float w1s[256];                // w1 in LDS (lgkm domain)

    const int tid  = threadIdx.x;
    const int lane = tid & 63;
    const int w    = tid >> 6;                // wave 0..7

    // XCD-locality decode: id%8 constant across the jt group and the is group
    const int id = blockIdx.x;                // 0..511
    const int b  = id & 15;                   // batch
    const int is = (id >> 4) & 3;             // i slice (0..3), 256 rows
    const int jt = id >> 6;                   // j tile (0..7), 128 cols

    const int i0blk = is * 256;
    const float* gX = x + ((size_t)b * TT + i0blk) * DK;

    // DMA geometry: chunk q = w*4 + t covers panel rows q*8..q*8+8 (1KB LDS,
    // one global_load_lds x 64 lanes x 16B). LDS dest wave-uniform; global
    // src per-lane, chunk-XOR-swizzled (rule 21; verified correct in R11).
    const int r_ln = lane >> 3;               // row within 8-row chunk
    const int c_ln = lane & 7;                // 16B slot within row

    // ---- 0. issue DMA for panels 0 and 1 (drained by the stage barrier)
    #pragma unroll
    for (int p = 0; p < 2; ++p) {
        #pragma unroll
        for (int t = 0; t < 4; ++t) {
            const int q = w * 4 + t;
            const int r = q * 8 + r_ln;                   // block-local row
            const int gc = c_ln ^ (r & 7);                // swizzled src chunk
            const float* gp = gX + (size_t)r * DK + p * 32 + gc * 4;
            float* lp = &Xp[p][q * 256];                  // wave-uniform
            __builtin_amdgcn_global_load_lds(
                (const __attribute__((address_space(1))) void*)gp,
                (__attribute__((address_space(3))) void*)lp, 16, 0, 0);
        }
    }

    // ---- 1. stage B = bf16(w3*y) (XOR-swizzled), ty = y.w2, w1 -> LDS
    if (tid < 64) {
        *(float4*)&w1s[tid * 4] = *(const float4*)&WS[tid * 4];
    }
    {
        const float* gY0 = y + ((size_t)b * TT + jt * 128) * DK;
        const int c = tid & 31;               // 16B chunk within row
        const float* w3p = WS + 2 * DK + c * 8;
        const float* w2p = WS + DK + c * 8;
        const float4 wa = *(const float4*)(w3p);
        const float4 wb = *(const float4*)(w3p + 4);
        const float4 va = *(const float4*)(w2p);
        const float4 vb = *(const float4*)(w2p + 4);
        #pragma unroll
        for (int it = 0; it < 8; ++it) {
            const int j = it * 16 + (tid >> 5);   // local row 0..127
            const float* gY = gY0 + (size_t)j * DK + c * 8;
            const float4 ya = *(const float4*)(gY);
            const float4 yb = *(const float4*)(gY + 4);
            float p = ya.x * va.x + ya.y * va.y + ya.z * va.z + ya.w * va.w
                    + yb.x * vb.x + yb.y * vb.y + yb.z * vb.z + yb.w * vb.w;
            uint4 o;
            o.x = cvt_pk_bf16(ya.x * wa.x, ya.y * wa.y);
            o.y = cvt_pk_bf16(ya.z * wa.z, ya.w * wa.w);
            o.z = cvt_pk_bf16(yb.x * wb.x, yb.y * wb.y);
            o.w = cvt_pk_bf16(yb.z * wb.z, yb.w * wb.w);
            const int slot = c ^ (j & 7);
            *(uint4*)(Bs + j * DK + slot * 8) = o;
            // reduce p across the 32 lanes sharing row j
            p += __shfl_xor(p, 1);
            p += __shfl_xor(p, 2);
            p += __shfl_xor(p, 4);
            p += __shfl_xor(p, 8);
            p += __shfl_xor(p, 16);
            if ((tid & 31) == 0) tys[j] = p;
        }
    }
    __syncthreads();   // the ONLY barrier: drains panels 0,1 + publishes LDS

    // ---- 2. barrier-free K-loop with counted vmcnt (panels wave-private)
    const int mfr  = lane & 15;
    const int quad = lane >> 4;
    const int Rl0  = w * 32 + mfr;            // block-local row, it=0
    const int Rl1  = Rl0 + 16;                // it=1

    f32x4 acc[2][8];
    #pragma unroll
    for (int it = 0; it < 2; ++it)
        #pragma unroll
        for (int n = 0; n < 8; ++n)
            acc[it][n] = (f32x4){0.f, 0.f, 0.f, 0.f};
    float txp[2] = {0.f, 0.f};

    #pragma unroll
    for (int ks = 0; ks < 8; ++ks) {
        // panel ks ready-gate: allow panel ks+1's 4 loads to stay in flight.
        // ks=0,1 ready via the barrier. ks=7: nothing else outstanding.
        if (ks >= 2) {
            if (ks == 7) asm volatile("s_waitcnt vmcnt(0)" ::: "memory");
            else         asm volatile("s_waitcnt vmcnt(4)" ::: "memory");
            __builtin_amdgcn_sched_barrier(0);
        }

        // read this wave's A-fragments from the private panel
        const float4 w1a = *(const float4*)&w1s[ks * 32 + quad * 8];
        const float4 w1b = *(const float4*)&w1s[ks * 32 + quad * 8 + 4];
        bf16x8 av[2];
        const int Rl[2] = {Rl0, Rl1};
        #pragma unroll
        for (int it = 0; it < 2; ++it) {
            const float* pr = &Xp[ks & 1][Rl[it] * 32];
            const int s0 = (quad * 2) ^ (Rl[it] & 7);
            const int s1 = (quad * 2 + 1) ^ (Rl[it] & 7);
            const float4 xa = *(const float4*)(pr + s0 * 4);
            const float4 xb = *(const float4*)(pr + s1 * 4);
            txp[it] += xa.x * w1a.x + xa.y * w1a.y + xa.z * w1a.z + xa.w * w1a.w
                     + xb.x * w1b.x + xb.y * w1b.y + xb.z * w1b.z + xb.w * w1b.w;
            BF8 cv;
            cv.u.x = cvt_pk_bf16(xa.x, xa.y);
            cv.u.y = cvt_pk_bf16(xa.z, xa.w);
            cv.u.z = cvt_pk_bf16(xb.x, xb.y);
            cv.u.w = cvt_pk_bf16(xb.z, xb.w);
            av[it] = cv.v;
        }

        // buffer ks&1 consumed (frags in regs) -> issue DMA for panel ks+2.
        // Issue-to-use distance: rest of this iter + all of iter ks+1.
        if (ks < 6) {
            #pragma unroll
            for (int t = 0; t < 4; ++t) {
                const int q = w * 4 + t;
                const int r = q * 8 + r_ln;
                const int gc = c_ln ^ (r & 7);
                const float* gp = gX + (size_t)r * DK + (ks + 2) * 32 + gc * 4;
                float* lp = &Xp[ks & 1][q * 256];
                __builtin_amdgcn_global_load_lds(
                    (const __attribute__((address_space(1))) void*)gp,
                    (__attribute__((address_space(3))) void*)lp, 16, 0, 0);
            }
        }

        // MFMA cluster
        #pragma unroll
        for (int n = 0; n < 8; ++n) {
            const int j    = n * 16 + mfr;
            const int slot = (ks * 4 + quad) ^ (j & 7);
            const bf16x8 bv = *(const bf16x8*)(Bs + j * DK + slot * 8);
            #pragma unroll
            for (int it = 0; it < 2; ++it)
                acc[it][n] = __builtin_amdgcn_mfma_f32_16x16x32_bf16(
                    av[it], bv, acc[it][n], 0, 0, 0);
        }
    }

    // ---- 3. epilogue: tx quad-reduction, + tx[i] + ty[j], fp32 stores
    #pragma unroll
    for (int it = 0; it < 2; ++it) {
        txp[it] += __shfl_xor(txp[it], 16);
        txp[it] += __shfl_xor(txp[it], 32);
        // lane now holds full tx for row i0 + it*16 + mfr
    }

    float tyv[8];
    #pragma unroll
    for (int n = 0; n < 8; ++n)
        tyv[n] = tys[n * 16 + mfr];

    const int i0 = i0blk + w * 32;
    float* outB = out + ((size_t)b << 20) + (size_t)i0 * TT + jt * 128;
    #pragma unroll
    for (int it = 0; it < 2; ++it) {
        #pragma unroll
        for (int r = 0; r < 4; ++r) {
            const int row = it * 16 + quad * 4 + r;
            // tx for this row lives at lanes with mfr == quad*4+r (any quad)
            const float trow = __shfl(txp[it], (lane & 48) | (quad * 4 + r));
            #pragma unroll
            for (int n = 0; n < 8; ++n)
                outB[(size_t)row * TT + n * 16 + mfr] =
                    acc[it][n][r] + trow + tyv[n];
        }
    }
}

extern "C" void kernel_launch(void* const* d_in, const int* in_sizes, int n_in,
                              void* d_out, int out_size, void* d_ws, size_t ws_size,
                              hipStream_t stream)
{
    const float* x  = (const float*)d_in[0];
    const float* y  = (const float*)d_in[1];
    const float* WS = (const float*)d_in[2];
    float* out = (float*)d_out;
    (void)d_ws; (void)ws_size;   // no workspace needed — fully fused

    fused_kernel<<<dim3(512), dim3(512), 0, stream>>>(x, y, WS, out);
}

// Round 8
// 108.959 us; speedup vs baseline: 1.1576x; 1.0841x over previous
//
#include <hip/hip_runtime.h>

#define DK 256   // feature dim (K)
#define TT 1024  // T1 = T2
#define NB 16    // batch

typedef __attribute__((ext_vector_type(8))) short bf16x8;
typedef __attribute__((ext_vector_type(4))) float f32x4;

// HW packed fp32->bf16 (RNE). r[15:0]=bf16(lo), r[31:16]=bf16(hi).
__device__ __forceinline__ unsigned int cvt_pk_bf16(float lo, float hi) {
    unsigned int r;
    asm("v_cvt_pk_bf16_f32 %0, %1, %2" : "=v"(r) : "v"(lo), "v"(hi));
    return r;
}

union BF8 { uint4 u; bf16x8 v; };

// ---------------------------------------------------------------------------
// R13: two-kernel split via d_ws. Session post-mortem (R9..R12): every
// latency-hiding attempt (reg prefetch, DMA panels, counted vmcnt) lost to
// plain R6 (~39us) -- the structural waste is that x is re-read AND
// re-converted fp32->bf16 8x, y 4x, inside the hot kernel (268MB traffic,
// 200M conversions). Fix the redundancy instead of hiding it:
//  * prep_kernel (~10us, HBM-bound): xb=bf16(x), yb=bf16(w3*y) into ws,
//    plus tx=x.w1, ty=y.w2 precomputed (per-wave shfl reduce).
//  * gemm_kernel: R6 skeleton, bf16 inputs. A-frags load DIRECTLY from
//    global (16B bf16x8, no cvt, no w1 work); y-stage is a pure swizzled
//    16B copy; tx/ty staged to LDS (epilogue shfl gone). K-loop bytes
//    halve; load->MFMA chain loses its VALU stage; regs drop -> compiler
//    can hoist A-loads at (512,4).
//  * Fallback: ws too small -> launch R6 kernel unchanged.
// ---------------------------------------------------------------------------

// ---- kernel 1: convert + row-reduction prep ----
__global__ __launch_bounds__(256) void prep_kernel(
    const float* __restrict__ x, const float* __restrict__ y,
    const float* __restrict__ WS,
    unsigned short* __restrict__ xb, unsigned short* __restrict__ yb,
    float* __restrict__ tx, float* __restrict__ ty)
{
    const int lane = threadIdx.x & 63;
    const int gw   = blockIdx.x * 4 + (threadIdx.x >> 6); // wave 0..32767
    const int r    = gw & 16383;                          // row 0..16383
    const bool isx = gw < 16384;

    const float* src = (isx ? x : y) + (size_t)r * DK + lane * 4;
    const float4 v  = *(const float4*)src;
    const float4 wd = *(const float4*)(WS + (isx ? 0 : DK) + lane * 4);

    float dot = v.x * wd.x + v.y * wd.y + v.z * wd.z + v.w * wd.w;
    dot += __shfl_xor(dot, 1);
    dot += __shfl_xor(dot, 2);
    dot += __shfl_xor(dot, 4);
    dot += __shfl_xor(dot, 8);
    dot += __shfl_xor(dot, 16);
    dot += __shfl_xor(dot, 32);

    float4 s = v;
    if (!isx) {
        const float4 w3 = *(const float4*)(WS + 2 * DK + lane * 4);
        s.x = v.x * w3.x; s.y = v.y * w3.y; s.z = v.z * w3.z; s.w = v.w * w3.w;
    }
    uint2 o;
    o.x = cvt_pk_bf16(s.x, s.y);
    o.y = cvt_pk_bf16(s.z, s.w);
    unsigned short* dst = (isx ? xb : yb) + (size_t)r * DK + lane * 4;
    *(uint2*)dst = o;                          // 8B coalesced
    if (lane == 0) (isx ? tx : ty)[r] = dot;
}

// ---- kernel 2: bf16 GEMM + rank-1 additions (R6 skeleton) ----
__global__ __launch_bounds__(512, 4) void gemm_kernel(
    const unsigned short* __restrict__ xb, const unsigned short* __restrict__ yb,
    const float* __restrict__ tx, const float* __restrict__ ty,
    float* __restrict__ out)
{
    __shared__ unsigned short Bs[128 * DK];   // 64 KB, XOR-swizzled
    __shared__ float txs[256];
    __shared__ float tys[128];

    const int tid  = threadIdx.x;
    const int lane = tid & 63;
    const int w    = tid >> 6;                // wave 0..7

    // XCD-locality decode (as R6): id%8 constant across jt and is groups
    const int id = blockIdx.x;                // 0..511
    const int b  = id & 15;                   // batch
    const int is = (id >> 4) & 3;             // i slice (0..3), 256 rows
    const int jt = id >> 6;                   // j tile (0..7), 128 cols

    // ---- 1. stage Bs = yb tile (swizzled copy), txs/tys slices
    {
        const unsigned short* gY = yb + ((size_t)b * TT + jt * 128) * DK;
        #pragma unroll
        for (int it = 0; it < 8; ++it) {
            const int g = it * 512 + tid;     // 16B chunk 0..4095
            const int j = g >> 5;             // local row 0..127
            const int c = g & 31;             // k-chunk 0..31
            const uint4 o = *(const uint4*)(gY + (size_t)j * DK + c * 8);
            *(uint4*)(Bs + j * DK + ((c ^ (j & 7)) * 8)) = o;
        }
        if (tid < 64)
            *(float4*)&txs[tid * 4] =
                *(const float4*)(tx + b * TT + is * 256 + tid * 4);
        else if (tid < 96)
            *(float4*)&tys[(tid - 64) * 4] =
                *(const float4*)(ty + b * TT + jt * 128 + (tid - 64) * 4);
    }
    __syncthreads();                          // the ONLY barrier

    // ---- 2. K-loop: A-frags direct from global bf16, no conversion
    const int mfr  = lane & 15;
    const int quad = lane >> 4;
    const int i0   = is * 256 + w * 32;
    const unsigned short* gA = xb + ((size_t)b * TT + i0) * DK;

    f32x4 acc[2][8];
    #pragma unroll
    for (int it = 0; it < 2; ++it)
        #pragma unroll
        for (int n = 0; n < 8; ++n)
            acc[it][n] = (f32x4){0.f, 0.f, 0.f, 0.f};

    #pragma unroll
    for (int ks = 0; ks < 8; ++ks) {
        bf16x8 av[2];
        #pragma unroll
        for (int it = 0; it < 2; ++it) {
            BF8 cv;
            cv.u = *(const uint4*)(gA + (size_t)(it * 16 + mfr) * DK
                                   + ks * 32 + quad * 8);
            av[it] = cv.v;
        }
        #pragma unroll
        for (int n = 0; n < 8; ++n) {
            const int j    = n * 16 + mfr;
            const int slot = (ks * 4 + quad) ^ (j & 7);
            const bf16x8 bv = *(const bf16x8*)(Bs + j * DK + slot * 8);
            #pragma unroll
            for (int it = 0; it < 2; ++it)
                acc[it][n] = __builtin_amdgcn_mfma_f32_16x16x32_bf16(
                    av[it], bv, acc[it][n], 0, 0, 0);
        }
    }

    // ---- 3. epilogue: + tx[i] + ty[j] from LDS (no shfl), fp32 stores
    float tyv[8];
    #pragma unroll
    for (int n = 0; n < 8; ++n)
        tyv[n] = tys[n * 16 + mfr];

    float* outB = out + ((size_t)b << 20) + (size_t)i0 * TT + jt * 128;
    #pragma unroll
    for (int it = 0; it < 2; ++it) {
        #pragma unroll
        for (int r = 0; r < 4; ++r) {
            const int row  = it * 16 + quad * 4 + r;
            const float trow = txs[w * 32 + row];
            #pragma unroll
            for (int n = 0; n < 8; ++n)
                outB[(size_t)row * TT + n * 16 + mfr] =
                    acc[it][n][r] + trow + tyv[n];
        }
    }
}

// ---- fallback: exact R6 fused kernel (used only if ws is too small) ----
__global__ __launch_bounds__(512, 4) void fused_kernel(
    const float* __restrict__ x, const float* __restrict__ y,
    const float* __restrict__ WS, float* __restrict__ out)
{
    __shared__ unsigned short Bs[128 * DK];
    __shared__ float tys[128];

    const int tid  = threadIdx.x;
    const int lane = tid & 63;
    const int w    = tid >> 6;

    const int id = blockIdx.x;
    const int b  = id & 15;
    const int is = (id >> 4) & 3;
    const int jt = id >> 6;

    {
        const float* gY0 = y + ((size_t)b * TT + jt * 128) * DK;
        const int c = tid & 31;
        const float* w3p = WS + 2 * DK + c * 8;
        const float* w2p = WS + DK + c * 8;
        const float4 wa = *(const float4*)(w3p);
        const float4 wb = *(const float4*)(w3p + 4);
        const float4 va = *(const float4*)(w2p);
        const float4 vb = *(const float4*)(w2p + 4);
        #pragma unroll
        for (int it = 0; it < 8; ++it) {
            const int j = it * 16 + (tid >> 5);
            const float* gY = gY0 + (size_t)j * DK + c * 8;
            const float4 ya = *(const float4*)(gY);
            const float4 yb2 = *(const float4*)(gY + 4);
            float p = ya.x * va.x + ya.y * va.y + ya.z * va.z + ya.w * va.w
                    + yb2.x * vb.x + yb2.y * vb.y + yb2.z * vb.z + yb2.w * vb.w;
            uint4 o;
            o.x = cvt_pk_bf16(ya.x * wa.x, ya.y * wa.y);
            o.y = cvt_pk_bf16(ya.z * wa.z, ya.w * wa.w);
            o.z = cvt_pk_bf16(yb2.x * wb.x, yb2.y * wb.y);
            o.w = cvt_pk_bf16(yb2.z * wb.z, yb2.w * wb.w);
            const int slot = c ^ (j & 7);
            *(uint4*)(Bs + j * DK + slot * 8) = o;
            p += __shfl_xor(p, 1);
            p += __shfl_xor(p, 2);
            p += __shfl_xor(p, 4);
            p += __shfl_xor(p, 8);
            p += __shfl_xor(p, 16);
            if ((tid & 31) == 0) tys[j] = p;
        }
    }
    __syncthreads();

    const int mfr  = lane & 15;
    const int quad = lane >> 4;
    const int i0   = is * 256 + w * 32;
    const float* gA = x + ((size_t)b * TT + i0) * DK;

    f32x4 acc[2][8];
    #pragma unroll
    for (int it = 0; it < 2; ++it)
        #pragma unroll
        for (int n = 0; n < 8; ++n)
            acc[it][n] = (f32x4){0.f, 0.f, 0.f, 0.f};
    float txp[2] = {0.f, 0.f};

    #pragma unroll
    for (int ks = 0; ks < 8; ++ks) {
        const float* w1p = WS + ks * 32 + quad * 8;
        const float4 w1a = *(const float4*)(w1p);
        const float4 w1b = *(const float4*)(w1p + 4);
        bf16x8 av[2];
        #pragma unroll
        for (int it = 0; it < 2; ++it) {
            const float* rp = gA + (size_t)(it * 16 + mfr) * DK
                              + ks * 32 + quad * 8;
            const float4 xa = *(const float4*)rp;
            const float4 xb2 = *(const float4*)(rp + 4);
            txp[it] += xa.x * w1a.x + xa.y * w1a.y + xa.z * w1a.z + xa.w * w1a.w
                     + xb2.x * w1b.x + xb2.y * w1b.y + xb2.z * w1b.z + xb2.w * w1b.w;
            BF8 cv;
            cv.u.x = cvt_pk_bf16(xa.x, xa.y);
            cv.u.y = cvt_pk_bf16(xa.z, xa.w);
            cv.u.z = cvt_pk_bf16(xb2.x, xb2.y);
            cv.u.w = cvt_pk_bf16(xb2.z, xb2.w);
            av[it] = cv.v;
        }
        #pragma unroll
        for (int n = 0; n < 8; ++n) {
            const int j    = n * 16 + mfr;
            const int slot = (ks * 4 + quad) ^ (j & 7);
            const bf16x8 bv = *(const bf16x8*)(Bs + j * DK + slot * 8);
            #pragma unroll
            for (int it = 0; it < 2; ++it)
                acc[it][n] = __builtin_amdgcn_mfma_f32_16x16x32_bf16(
                    av[it], bv, acc[it][n], 0, 0, 0);
        }
    }

    #pragma unroll
    for (int it = 0; it < 2; ++it) {
        txp[it] += __shfl_xor(txp[it], 16);
        txp[it] += __shfl_xor(txp[it], 32);
    }

    float tyv[8];
    #pragma unroll
    for (int n = 0; n < 8; ++n)
        tyv[n] = tys[n * 16 + mfr];

    float* outB = out + ((size_t)b << 20) + (size_t)i0 * TT + jt * 128;
    #pragma unroll
    for (int it = 0; it < 2; ++it) {
        #pragma unroll
        for (int r = 0; r < 4; ++r) {
            const int row = it * 16 + quad * 4 + r;
            const float trow = __shfl(txp[it], (lane & 48) | (quad * 4 + r));
            #pragma unroll
            for (int n = 0; n < 8; ++n)
                outB[(size_t)row * TT + n * 16 + mfr] =
                    acc[it][n][r] + trow + tyv[n];
        }
    }
}

extern "C" void kernel_launch(void* const* d_in, const int* in_sizes, int n_in,
                              void* d_out, int out_size, void* d_ws, size_t ws_size,
                              hipStream_t stream)
{
    const float* x  = (const float*)d_in[0];
    const float* y  = (const float*)d_in[1];
    const float* WS = (const float*)d_in[2];
    float* out = (float*)d_out;

    // ws layout (bytes): xb[8388608] | yb[8388608] | tx[65536] | ty[65536]
    const size_t XB_OFF = 0;
    const size_t YB_OFF = 8388608;
    const size_t TX_OFF = 16777216;
    const size_t TY_OFF = 16842752;
    const size_t NEED   = 16908288;

    if (ws_size >= NEED && d_ws != nullptr) {
        unsigned short* xb = (unsigned short*)((char*)d_ws + XB_OFF);
        unsigned short* yb = (unsigned short*)((char*)d_ws + YB_OFF);
        float* tx = (float*)((char*)d_ws + TX_OFF);
        float* ty = (float*)((char*)d_ws + TY_OFF);
        prep_kernel<<<dim3(8192), dim3(256), 0, stream>>>(x, y, WS, xb, yb, tx, ty);
        gemm_kernel<<<dim3(512), dim3(512), 0, stream>>>(xb, yb, tx, ty, out);
    } else {
        fused_kernel<<<dim3(512), dim3(512), 0, stream>>>(x, y, WS, out);
    }
}